// Round 8
// baseline (1114.588 us; speedup 1.0000x reference)
//
#include <hip/hip_runtime.h>

#define DI __device__ __forceinline__

typedef unsigned int uint;
typedef unsigned short ushort;
typedef _Float16 half2t __attribute__((ext_vector_type(2)));

#define VOCAB 50257
#define NEMB 48
#define HID 128
#define G4 512
#define NCLS 2000
#define BATCH 512
#define SEQ 1024

#if __has_builtin(__builtin_amdgcn_fdot2)
DI float fdot2(half2t a, half2t b, float c) { return __builtin_amdgcn_fdot2(a, b, c, false); }
#else
DI float fdot2(half2t a, half2t b, float c) { return c + (float)a.x * (float)b.x + (float)a.y * (float)b.y; }
#endif

#define LOG2E 1.4426950408889634f

// DPP quad helpers (VALU pipe)
DI float dppx1(float v) {  // lane ^ 1
  return __builtin_bit_cast(float,
      __builtin_amdgcn_update_dpp(0, __builtin_bit_cast(int, v), 0xB1, 0xF, 0xF, true));
}
DI float dppx2(float v) {  // lane ^ 2
  return __builtin_bit_cast(float,
      __builtin_amdgcn_update_dpp(0, __builtin_bit_cast(int, v), 0x4E, 0xF, 0xF, true));
}
DI float dppb3(float v) {  // broadcast quad-lane 3
  return __builtin_bit_cast(float,
      __builtin_amdgcn_update_dpp(0, __builtin_bit_cast(int, v), 0xFF, 0xF, 0xF, true));
}

// LDS-only barrier: orders LDS (lgkm) across the block WITHOUT draining vmcnt,
// so in-flight global prefetches survive the barrier.
DI void bar_lds() { asm volatile("s_waitcnt lgkmcnt(0)\n\ts_barrier" ::: "memory"); }

// ---------------------------------------------------------------------------
// Phase A: P3[v][g*128+u] = emb[v].w_ih[g*128+u] + b_ih + b_hh  (f16, natural
// gate-major order = w_ih row order).
// ---------------------------------------------------------------------------
#define VROWS 32
__global__ __launch_bounds__(512) void build_P(
    const float* __restrict__ emb, const float* __restrict__ w_ih,
    const float* __restrict__ b_ih, const float* __restrict__ b_hh,
    ushort* __restrict__ P3)
{
  __shared__ __align__(16) float eL[VROWS][NEMB];
  const int tid = threadIdx.x;
  const int v0 = blockIdx.x * VROWS;
  int nrows = VOCAB - v0; if (nrows > VROWS) nrows = VROWS;

  for (int f = tid; f < nrows * NEMB; f += 512)
    eL[f / NEMB][f % NEMB] = emb[(size_t)v0 * NEMB + f];

  float w[NEMB];
  {
    const float* wr = w_ih + (size_t)tid * NEMB;
#pragma unroll
    for (int k = 0; k < NEMB; k++) w[k] = wr[k];
  }
  float bias = b_ih[tid] + b_hh[tid];
  __syncthreads();

  for (int v = 0; v < nrows; v++) {
    const float4* e4 = (const float4*)&eL[v][0];
    float a = bias;
#pragma unroll
    for (int k = 0; k < NEMB / 4; k++) {
      float4 e = e4[k];
      a += w[4 * k] * e.x + w[4 * k + 1] * e.y + w[4 * k + 2] * e.z + w[4 * k + 3] * e.w;
    }
    P3[(size_t)(v0 + v) * G4 + tid] = __builtin_bit_cast(ushort, (_Float16)a);
  }
}

// ---------------------------------------------------------------------------
// Phase B: persistent LSTM scan. 512 blocks x 512 threads (1 row/block,
// 2 blocks/CU, 4 waves/SIMD). Thread (u=tid>>2, q=tid&3) dots unit u's 4 gate
// rows over k in [32q,32q+32) (64 fdot2, 4 broadcast ds_read_b128), then a
// cndmask-steered 2-stage DPP transpose-reduce leaves gate q's pre-act in
// lane q. Unified sigma/tanh (2 trans/lane/step). c lives in lane 0 of each
// quad. LDS-only barrier + 4-deep P3 prefetch. launch_bounds(512,3): 170-VGPR
// cap so the 64-VGPR w[] array stays in ARCH VGPRs (at (512,4)/128 the
// allocator parked w in AGPRs and paid v_accvgpr_read per use -> 2.3x VALU).
// tokPad holds PRE-SCALED byte offsets (tok*1024 = P3 row) so the gather is
// one v_add_u32 + saddr global_load_ushort.
// ---------------------------------------------------------------------------
template<bool USE_P>
__global__ __launch_bounds__(512, 3) void lstm_scan(
    const int* __restrict__ x, const float* __restrict__ emb,
    const float* __restrict__ w_ih, const float* __restrict__ w_hh,
    const float* __restrict__ b_ih, const float* __restrict__ b_hh,
    const ushort* __restrict__ P3, float* __restrict__ hout)
{
  __shared__ int tokPad[SEQ + 4];
  __shared__ __align__(16) _Float16 h16[2][HID];
  __shared__ __align__(8) half2t e16[2][NEMB / 2];

  const int tid = threadIdx.x;
  const int b   = blockIdx.x;
  const int u   = tid >> 2;        // unit
  const int q   = tid & 3;         // gate owned after reduce / k-quarter
  const bool par1 = (q & 1) != 0;
  const bool par2 = (q & 2) != 0;
  const uint goffb = (uint)(((q << 7) + u) * 2);   // byte offset within P3 row

  // unified activation constants: gates 0,1,3 sigmoid; gate 2 tanh
  const bool isg = (q == 2);
  const float mk = isg ? (2.0f * LOG2E) : (-LOG2E);
  const float av = isg ? -2.0f : 1.0f;
  const float bv = isg ? 1.0f : 0.0f;

  {
    const int* xp = x + (size_t)b * SEQ;
    // USE_P: store byte offset of the P3 row (tok * 1024); else raw token.
    tokPad[tid]       = USE_P ? (xp[tid] << 10)       : xp[tid];
    tokPad[tid + 512] = USE_P ? (xp[tid + 512] << 10) : xp[tid + 512];
    if (tid < 4) tokPad[SEQ + tid] = USE_P ? (xp[SEQ - 1] << 10) : xp[SEQ - 1];
  }

  // W_hh fragments: gates i,f,g,o of unit u, k in [32q, 32q+32): 64 VGPRs.
  half2t w[4][16];
#pragma unroll
  for (int g = 0; g < 4; g++) {
    const float4* wr = (const float4*)(w_hh + (size_t)(g * HID + u) * HID + 32 * q);
#pragma unroll
    for (int k4 = 0; k4 < 8; k4++) {
      float4 v = wr[k4];
      half2t p;
      p.x = (_Float16)v.x; p.y = (_Float16)v.y; w[g][2 * k4] = p;
      p.x = (_Float16)v.z; p.y = (_Float16)v.w; w[g][2 * k4 + 1] = p;
    }
  }

  // Fallback: this lane's single gate row of w_ih (full K=48) + bias.
  half2t wihq[NEMB / 2];
  float biasq = 0.0f;
  if (!USE_P) {
    const float* wr = w_ih + (size_t)(q * HID + u) * NEMB;
#pragma unroll
    for (int k = 0; k < NEMB / 2; k++) {
      half2t p; p.x = (_Float16)wr[2 * k]; p.y = (_Float16)wr[2 * k + 1];
      wihq[k] = p;
    }
    biasq = b_ih[q * HID + u] + b_hh[q * HID + u];
  }
  if (tid < HID) h16[1][tid] = (_Float16)0.0f;   // step 0 reads buf 1
  __syncthreads();  // init barrier (full drain once is fine)

  const char* P3c = (const char*)P3;

  float c = 0.0f;
  ushort pr0 = 0, pr1 = 0, pr2 = 0, pr3 = 0;
  float2 einfl = {0.0f, 0.0f};
  if (USE_P) {
    pr0 = *(const ushort*)(P3c + ((uint)tokPad[0] + goffb));
    pr1 = *(const ushort*)(P3c + ((uint)tokPad[1] + goffb));
    pr2 = *(const ushort*)(P3c + ((uint)tokPad[2] + goffb));
    pr3 = *(const ushort*)(P3c + ((uint)tokPad[3] + goffb));
  } else {
    if (tid < NEMB / 2) {
      float2 e0 = ((const float2*)(emb + (size_t)tokPad[0] * NEMB))[tid];
      einfl     = ((const float2*)(emb + (size_t)tokPad[1] * NEMB))[tid];
      half2t p; p.x = (_Float16)e0.x; p.y = (_Float16)e0.y;
      e16[0][tid] = p;
    }
    __syncthreads();
  }

// One timestep; tt = t + jpar, jpar is a 0..3 literal, PRJ names the
// prefetch register for this phase (consumed now, refilled for tt+4).
#define STEP(tt, jpar, PRJ) do {                                               \
    ushort cur = PRJ;                                                          \
    if (USE_P) {                                                               \
      uint off4 = (uint)tokPad[(tt) + 4] + goffb;                              \
      PRJ = *(const ushort*)(P3c + off4);  /* prefetch t+4, no drain */        \
    } else {                                                                   \
      if (tid < NEMB / 2) {                                                    \
        half2t p; p.x = (_Float16)einfl.x; p.y = (_Float16)einfl.y;            \
        e16[((tt) + 1) & 1][tid] = p;                                          \
        einfl = ((const float2*)(emb + (size_t)tokPad[(tt) + 2] * NEMB))[tid]; \
      }                                                                        \
    }                                                                          \
    const uint4* hv = (const uint4*)(&h16[((jpar) + 1) & 1][32 * q]);          \
    float a0 = 0.f, a1 = 0.f, a2 = 0.f, a3 = 0.f;                              \
    _Pragma("unroll")                                                          \
    for (int q4 = 0; q4 < 4; q4++) {                                           \
      uint4 hq = hv[q4];                                                       \
      half2t h0 = __builtin_bit_cast(half2t, hq.x);                            \
      half2t h1 = __builtin_bit_cast(half2t, hq.y);                            \
      half2t h2 = __builtin_bit_cast(half2t, hq.z);                            \
      half2t h3 = __builtin_bit_cast(half2t, hq.w);                            \
      a0 = fdot2(w[0][4*q4+0], h0, a0); a1 = fdot2(w[1][4*q4+0], h0, a1);      \
      a2 = fdot2(w[2][4*q4+0], h0, a2); a3 = fdot2(w[3][4*q4+0], h0, a3);      \
      a0 = fdot2(w[0][4*q4+1], h1, a0); a1 = fdot2(w[1][4*q4+1], h1, a1);      \
      a2 = fdot2(w[2][4*q4+1], h1, a2); a3 = fdot2(w[3][4*q4+1], h1, a3);      \
      a0 = fdot2(w[0][4*q4+2], h2, a0); a1 = fdot2(w[1][4*q4+2], h2, a1);      \
      a2 = fdot2(w[2][4*q4+2], h2, a2); a3 = fdot2(w[3][4*q4+2], h2, a3);      \
      a0 = fdot2(w[0][4*q4+3], h3, a0); a1 = fdot2(w[1][4*q4+3], h3, a1);      \
      a2 = fdot2(w[2][4*q4+3], h3, a2); a3 = fdot2(w[3][4*q4+3], h3, a3);      \
    }                                                                          \
    /* transpose-reduce: lane q <- full pre-act of gate q */                   \
    float kA = par1 ? a1 : a0, sA = par1 ? a0 : a1; kA += dppx1(sA);           \
    float kB = par1 ? a3 : a2, sB = par1 ? a2 : a3; kB += dppx1(sB);           \
    float kF = par2 ? kB : kA, sF = par2 ? kA : kB; kF += dppx2(sF);           \
    float xg;                                                                  \
    if (USE_P) {                                                               \
      xg = (float)__builtin_bit_cast(_Float16, cur);                           \
    } else {                                                                   \
      xg = biasq;                                                              \
      _Pragma("unroll")                                                        \
      for (int k = 0; k < NEMB / 2; k++)                                       \
        xg = fdot2(wihq[k], e16[(jpar) & 1][k], xg);                           \
    }                                                                          \
    float gv = kF + xg;                                                        \
    float act = av * __builtin_amdgcn_rcpf(                                    \
                    __builtin_amdgcn_exp2f(mk * gv) + 1.0f) + bv;              \
    float gt = dppx2(act);          /* lane0: tanh(g) */                       \
    float sf = dppx1(act);          /* lane0: sigma(f) */                      \
    c = act * gt + sf * c;          /* valid in lane 0 */                      \
    float tanhc = 1.0f - 2.0f * __builtin_amdgcn_rcpf(                         \
                    __builtin_amdgcn_exp2f(2.0f * LOG2E * c) + 1.0f);          \
    float so = dppb3(act);          /* sigma(o) everywhere */                  \
    float hh = so * tanhc;          /* valid in lane 0 */                      \
    if (q == 0) {                                                              \
      h16[(jpar) & 1][u] = (_Float16)hh;                                       \
      if ((tt) == SEQ - 1) hout[(size_t)b * HID + u] = hh;                     \
    }                                                                          \
    bar_lds();                                                                 \
  } while (0)

  for (int t = 0; t < SEQ; t += 4) {
    STEP(t, 0, pr0);
    STEP(t + 1, 1, pr1);
    STEP(t + 2, 2, pr2);
    STEP(t + 3, 3, pr3);
  }
#undef STEP
}

// ---------------------------------------------------------------------------
// Phase C: FC  out[512,2000] = h[512,128] @ w_fc^T + b_fc.  64x64 tiles.
// ---------------------------------------------------------------------------
#define FCR 64
#define FCC 64
__global__ __launch_bounds__(256) void fc_kernel(
    const float* __restrict__ h, const float* __restrict__ w_fc,
    const float* __restrict__ b_fc, float* __restrict__ out)
{
  __shared__ float aT[HID][FCR];
  __shared__ float bT[HID][FCC];
  const int tid = threadIdx.x;
  const int r0 = blockIdx.y * FCR;
  const int c0 = blockIdx.x * FCC;

  for (int f = tid; f < FCR * (HID / 4); f += 256) {
    int row = f >> 5, qq = f & 31;
    float4 v = ((const float4*)h)[(((size_t)(r0 + row)) << 5) + qq];
    aT[4 * qq + 0][row] = v.x; aT[4 * qq + 1][row] = v.y;
    aT[4 * qq + 2][row] = v.z; aT[4 * qq + 3][row] = v.w;
    int wrow = c0 + row;
    float4 wv;
    if (wrow < NCLS) wv = ((const float4*)w_fc)[(((size_t)wrow) << 5) + qq];
    else { wv.x = 0.f; wv.y = 0.f; wv.z = 0.f; wv.w = 0.f; }
    bT[4 * qq + 0][row] = wv.x; bT[4 * qq + 1][row] = wv.y;
    bT[4 * qq + 2][row] = wv.z; bT[4 * qq + 3][row] = wv.w;
  }
  __syncthreads();

  const int cr = tid & 15, rr = tid >> 4;
  float acc[4][4];
#pragma unroll
  for (int i = 0; i < 4; i++)
#pragma unroll
    for (int j = 0; j < 4; j++) acc[i][j] = 0.0f;

#pragma unroll 4
  for (int k = 0; k < HID; k++) {
    float4 av = *(const float4*)&aT[k][4 * rr];
    float4 bv = *(const float4*)&bT[k][4 * cr];
    float a[4] = {av.x, av.y, av.z, av.w};
    float bb[4] = {bv.x, bv.y, bv.z, bv.w};
#pragma unroll
    for (int i = 0; i < 4; i++)
#pragma unroll
      for (int j = 0; j < 4; j++) acc[i][j] += a[i] * bb[j];
  }

#pragma unroll
  for (int j = 0; j < 4; j++) {
    int cc = c0 + 4 * cr + j;
    if (cc < NCLS) {
      float bias = b_fc[cc];
#pragma unroll
      for (int i = 0; i < 4; i++)
        out[(size_t)(r0 + 4 * rr + i) * NCLS + cc] = acc[i][j] + bias;
    }
  }
}

extern "C" void kernel_launch(void* const* d_in, const int* in_sizes, int n_in,
                              void* d_out, int out_size, void* d_ws, size_t ws_size,
                              hipStream_t stream) {
  const int*   xx   = (const int*)d_in[0];
  const float* emb  = (const float*)d_in[1];
  const float* w_ih = (const float*)d_in[2];
  const float* w_hh = (const float*)d_in[3];
  const float* b_ih = (const float*)d_in[4];
  const float* b_hh = (const float*)d_in[5];
  const float* w_fc = (const float*)d_in[6];
  const float* b_fc = (const float*)d_in[7];
  float* out = (float*)d_out;

  const size_t pbytes = (size_t)VOCAB * G4 * sizeof(ushort); // 51.5 MB
  const size_t palign = (pbytes + 255) & ~(size_t)255;
  const size_t hbytes = (size_t)BATCH * HID * sizeof(float);

  float* hout;
  if (ws_size >= palign + hbytes) {
    ushort* P3 = (ushort*)d_ws;
    hout = (float*)((char*)d_ws + palign);
    build_P<<<(VOCAB + VROWS - 1) / VROWS, 512, 0, stream>>>(emb, w_ih, b_ih, b_hh, P3);
    lstm_scan<true><<<BATCH, 512, 0, stream>>>(xx, emb, w_ih, w_hh, b_ih, b_hh, P3, hout);
  } else {
    hout = (float*)d_ws;
    lstm_scan<false><<<BATCH, 512, 0, stream>>>(xx, emb, w_ih, w_hh, b_ih, b_hh,
                                                (const ushort*)nullptr, hout);
  }
  dim3 fcg((NCLS + FCC - 1) / FCC, BATCH / FCR);
  fc_kernel<<<fcg, 256, 0, stream>>>(hout, w_fc, b_fc, out);
}